// Round 2
// baseline (3094.884 us; speedup 1.0000x reference)
//
#include <hip/hip_runtime.h>
#include <stdint.h>
#include <math.h>

// ---------------------------------------------------------------------------
// Encoder: per-batch tiny attention with softmax over the BATCH axis (dim 0),
// joint [64,16] LayerNorm, 64 independent per-patch 2-layer MLPs, final LN.
//
// K0: G = Wq @ Wk^T / 3 ; pack W1/W2 to bf16
// K1: per-block online softmax stats (m, sumexp) over a chunk of batches
// K2: combine partials -> L[k][q] = m + ln(denom)   (transposed layout)
// K3: fused per-batch: scores -> attn -> z -> LN -> MLP -> LN -> out
// ---------------------------------------------------------------------------

__device__ __forceinline__ float rdlane_f(float v, int srclane) {
    return __uint_as_float((unsigned)__builtin_amdgcn_readlane((int)__float_as_uint(v), srclane));
}
__device__ __forceinline__ float bf16_lo(unsigned u) { return __uint_as_float(u << 16); }
__device__ __forceinline__ float bf16_hi(unsigned u) { return __uint_as_float(u & 0xffff0000u); }

// ---------------------------------------------------------------- K0: prep
__global__ void k0_prep(const float* __restrict__ Wq, const float* __restrict__ Wk,
                        const float* __restrict__ W1, const float* __restrict__ W2,
                        float* __restrict__ G, unsigned short* __restrict__ W1h,
                        unsigned short* __restrict__ W2h)
{
    const int t = threadIdx.x;
    {
        const int i = t >> 4, j = t & 15;
        float acc = 0.f;
        #pragma unroll
        for (int d = 0; d < 16; ++d) acc = fmaf(Wq[i*16 + d], Wk[j*16 + d], acc);
        G[i*16 + j] = acc * (1.0f / 3.0f);
    }
    for (int idx = t; idx < 16384; idx += 256) {
        const unsigned u1 = __float_as_uint(W1[idx]);   // round-to-nearest-even bf16
        W1h[idx] = (unsigned short)((u1 + 0x7fffu + ((u1 >> 16) & 1u)) >> 16);
        const unsigned u2 = __float_as_uint(W2[idx]);
        W2h[idx] = (unsigned short)((u2 + 0x7fffu + ((u2 >> 16) & 1u)) >> 16);
    }
}

// ------------------------------------------------- K1: online softmax stats
// lane = q (holds x[b][lane][:] and U[lane][:]); wave w owns k in [16w,16w+16)
// -> per-lane 16 (m,s) slots, constant mapping across batches.
__global__ __launch_bounds__(256, 2) void k1_stats(
    const float* __restrict__ x, const float* __restrict__ G,
    float* __restrict__ pm, float* __restrict__ ps, int batches_per_block)
{
    const int lane = threadIdx.x & 63;
    const int w    = threadIdx.x >> 6;

    float m_r[16], s_r[16];
    #pragma unroll
    for (int kk = 0; kk < 16; ++kk) { m_r[kk] = -INFINITY; s_r[kk] = 0.f; }

    const size_t b0 = (size_t)blockIdx.x * batches_per_block;
    for (int bi = 0; bi < batches_per_block; ++bi) {
        const float* xb = x + (b0 + bi) * 1024 + lane * 16;
        float xr[16];
        #pragma unroll
        for (int c = 0; c < 4; ++c) {
            const float4 v = *(const float4*)(xb + 4*c);
            xr[4*c+0] = v.x; xr[4*c+1] = v.y; xr[4*c+2] = v.z; xr[4*c+3] = v.w;
        }
        float U[16];
        #pragma unroll
        for (int j = 0; j < 16; ++j) U[j] = 0.f;
        #pragma unroll
        for (int i = 0; i < 16; ++i) {
            const float xi = xr[i];
            #pragma unroll
            for (int j = 0; j < 16; ++j) U[j] = fmaf(xi, G[i*16 + j], U[j]);
        }
        #pragma unroll
        for (int kk = 0; kk < 16; ++kk) {
            const int k = (w << 4) + kk;
            float s = 0.f;
            #pragma unroll
            for (int i = 0; i < 16; ++i) s = fmaf(rdlane_f(xr[i], k), U[i], s);
            if (s <= m_r[kk]) {
                s_r[kk] += __expf(s - m_r[kk]);
            } else {
                s_r[kk] = fmaf(s_r[kk], __expf(m_r[kk] - s), 1.0f);
                m_r[kk] = s;
            }
        }
    }
    // partials layout: pm[blk][k][q] (coalesced: lanes = q)
    float* pmb = pm + (size_t)blockIdx.x * 4096;
    float* psb = ps + (size_t)blockIdx.x * 4096;
    #pragma unroll
    for (int kk = 0; kk < 16; ++kk) {
        const int k = (w << 4) + kk;
        pmb[k*64 + lane] = m_r[kk];
        psb[k*64 + lane] = s_r[kk];
    }
}

// ------------------------------------------------ K2: combine -> L[k*64+q]
__global__ void k2_reduce(const float* __restrict__ pm, const float* __restrict__ ps,
                          float* __restrict__ LT, int nblocks)
{
    const int tid = blockIdx.x * 256 + threadIdx.x;   // 0..4095 == k*64+q
    float m = -INFINITY, s = 0.f;
    for (int blk = 0; blk < nblocks; ++blk) {
        const float mb = pm[(size_t)blk * 4096 + tid];
        const float sb = ps[(size_t)blk * 4096 + tid];
        if (mb <= m) {
            s += sb * __expf(mb - m);
        } else {
            s = fmaf(s, __expf(m - mb), sb);
            m = mb;
        }
    }
    LT[tid] = m + __logf(s);
}

// --------------------------------------------------------- K3: fused output
__global__ __launch_bounds__(256, 2) void k3_main(
    const float* __restrict__ x, const float* __restrict__ G,
    const float* __restrict__ Wv, const float* __restrict__ LT,
    const unsigned short* __restrict__ W1h, const float* __restrict__ b1,
    const unsigned short* __restrict__ W2h, const float* __restrict__ b2,
    float* __restrict__ out, int batches_per_block)
{
    __shared__ float zp[4][64][17];     // per-wave z partials (17: bank-conflict pad)
    __shared__ float y_lds[64][17];
    __shared__ float h_lds[64][17];
    __shared__ float red1[4][2];
    __shared__ float red2[4][2];

    const int lane = threadIdx.x & 63;  // = q / patch index
    const int w    = threadIdx.x >> 6;  // wave: k-slice for attn, o-slice for MLP
    const int o0   = w << 2;

    // resident per-thread MLP weights (bf16 packed): W1[p=lane][i][o0..o0+3]
    uint2 w1r[16], w2r[16];
    const uint2* W1v = (const uint2*)W1h;
    const uint2* W2v = (const uint2*)W2h;
    #pragma unroll
    for (int i = 0; i < 16; ++i) {
        const int eo = (lane*256 + i*16 + o0) >> 2;
        w1r[i] = W1v[eo];
        w2r[i] = W2v[eo];
    }
    const float4 b1r = *(const float4*)(b1 + lane*16 + o0);
    const float4 b2r = *(const float4*)(b2 + lane*16 + o0);

    for (int bi = 0; bi < batches_per_block; ++bi) {
        const size_t b = (size_t)blockIdx.x * batches_per_block + bi;
        const float* xb = x + b * 1024;

        float xr[16];
        #pragma unroll
        for (int c = 0; c < 4; ++c) {
            const float4 v = *(const float4*)(xb + lane*16 + 4*c);
            xr[4*c+0] = v.x; xr[4*c+1] = v.y; xr[4*c+2] = v.z; xr[4*c+3] = v.w;
        }
        // U = x@G (row per lane), V = x@Wv (row per lane); G/Wv via scalar loads
        float U[16], V[16];
        #pragma unroll
        for (int j = 0; j < 16; ++j) { U[j] = 0.f; V[j] = 0.f; }
        #pragma unroll
        for (int i = 0; i < 16; ++i) {
            const float xi = xr[i];
            #pragma unroll
            for (int j = 0; j < 16; ++j) {
                U[j] = fmaf(xi, G[i*16 + j],  U[j]);
                V[j] = fmaf(xi, Wv[i*16 + j], V[j]);
            }
        }
        // scores -> attn -> z partial over this wave's k-slice
        float z[16];
        #pragma unroll
        for (int d = 0; d < 16; ++d) z[d] = 0.f;
        #pragma unroll
        for (int kk = 0; kk < 16; ++kk) {
            const int k = (w << 4) + kk;
            float s = 0.f;
            #pragma unroll
            for (int i = 0; i < 16; ++i) s = fmaf(rdlane_f(xr[i], k), U[i], s);
            const float p = __expf(s - LT[k*64 + lane]);   // s <= max => no overflow
            #pragma unroll
            for (int d = 0; d < 16; ++d) z[d] = fmaf(p, rdlane_f(V[d], k), z[d]);
        }
        #pragma unroll
        for (int d = 0; d < 16; ++d) zp[w][lane][d] = z[d];
        __syncthreads();

        // t = x + z (thread owns (q=lane, d=o0..o0+3))
        float tv[4];
        {
            const float4 xre = *(const float4*)(xb + lane*16 + o0);
            const float xs[4] = {xre.x, xre.y, xre.z, xre.w};
            #pragma unroll
            for (int j = 0; j < 4; ++j)
                tv[j] = zp[0][lane][o0+j] + zp[1][lane][o0+j]
                      + zp[2][lane][o0+j] + zp[3][lane][o0+j] + xs[j];
        }
        // LN1 over all 1024 elements (biased var, eps 1e-5)
        float sm = tv[0] + tv[1] + tv[2] + tv[3];
        float sq = fmaf(tv[0], tv[0], fmaf(tv[1], tv[1], fmaf(tv[2], tv[2], tv[3]*tv[3])));
        #pragma unroll
        for (int off = 1; off < 64; off <<= 1) {
            sm += __shfl_xor(sm, off);
            sq += __shfl_xor(sq, off);
        }
        if (lane == 0) { red1[w][0] = sm; red1[w][1] = sq; }
        __syncthreads();
        {
            const float S  = red1[0][0] + red1[1][0] + red1[2][0] + red1[3][0];
            const float SS = red1[0][1] + red1[1][1] + red1[2][1] + red1[3][1];
            const float mean = S * (1.f/1024.f);
            const float var  = SS * (1.f/1024.f) - mean*mean;
            const float rinv = rsqrtf(var + 1e-5f);
            #pragma unroll
            for (int j = 0; j < 4; ++j) y_lds[lane][o0+j] = (tv[j] - mean) * rinv;
        }
        __syncthreads();

        // MLP layer 1: h = relu(y @ W1[p] + b1[p])
        float yrow[16];
        #pragma unroll
        for (int i = 0; i < 16; ++i) yrow[i] = y_lds[lane][i];
        float h0 = b1r.x, h1 = b1r.y, h2 = b1r.z, h3 = b1r.w;
        #pragma unroll
        for (int i = 0; i < 16; ++i) {
            const float yi = yrow[i];
            const uint2 ww = w1r[i];
            h0 = fmaf(yi, bf16_lo(ww.x), h0);
            h1 = fmaf(yi, bf16_hi(ww.x), h1);
            h2 = fmaf(yi, bf16_lo(ww.y), h2);
            h3 = fmaf(yi, bf16_hi(ww.y), h3);
        }
        h0 = fmaxf(h0, 0.f); h1 = fmaxf(h1, 0.f); h2 = fmaxf(h2, 0.f); h3 = fmaxf(h3, 0.f);
        h_lds[lane][o0+0] = h0; h_lds[lane][o0+1] = h1;
        h_lds[lane][o0+2] = h2; h_lds[lane][o0+3] = h3;
        __syncthreads();

        // MLP layer 2
        float hrow[16];
        #pragma unroll
        for (int i = 0; i < 16; ++i) hrow[i] = h_lds[lane][i];
        float g0 = b2r.x, g1 = b2r.y, g2 = b2r.z, g3 = b2r.w;
        #pragma unroll
        for (int i = 0; i < 16; ++i) {
            const float hi = hrow[i];
            const uint2 ww = w2r[i];
            g0 = fmaf(hi, bf16_lo(ww.x), g0);
            g1 = fmaf(hi, bf16_hi(ww.x), g1);
            g2 = fmaf(hi, bf16_lo(ww.y), g2);
            g3 = fmaf(hi, bf16_hi(ww.y), g3);
        }
        g0 = fmaxf(g0, 0.f); g1 = fmaxf(g1, 0.f); g2 = fmaxf(g2, 0.f); g3 = fmaxf(g3, 0.f);

        // residual + LN2
        float sv[4];
        sv[0] = g0 + y_lds[lane][o0+0];
        sv[1] = g1 + y_lds[lane][o0+1];
        sv[2] = g2 + y_lds[lane][o0+2];
        sv[3] = g3 + y_lds[lane][o0+3];
        float sm2 = sv[0] + sv[1] + sv[2] + sv[3];
        float sq2 = fmaf(sv[0], sv[0], fmaf(sv[1], sv[1], fmaf(sv[2], sv[2], sv[3]*sv[3])));
        #pragma unroll
        for (int off = 1; off < 64; off <<= 1) {
            sm2 += __shfl_xor(sm2, off);
            sq2 += __shfl_xor(sq2, off);
        }
        if (lane == 0) { red2[w][0] = sm2; red2[w][1] = sq2; }
        __syncthreads();
        {
            const float S  = red2[0][0] + red2[1][0] + red2[2][0] + red2[3][0];
            const float SS = red2[0][1] + red2[1][1] + red2[2][1] + red2[3][1];
            const float mean = S * (1.f/1024.f);
            const float var  = SS * (1.f/1024.f) - mean*mean;
            const float rinv = rsqrtf(var + 1e-5f);
            float4 ov;
            ov.x = (sv[0] - mean) * rinv;
            ov.y = (sv[1] - mean) * rinv;
            ov.z = (sv[2] - mean) * rinv;
            ov.w = (sv[3] - mean) * rinv;
            *(float4*)(out + b*1024 + lane*16 + o0) = ov;
        }
        __syncthreads();   // protect shared buffers before next batch
    }
}

// ---------------------------------------------------------------------------
extern "C" void kernel_launch(void* const* d_in, const int* in_sizes, int n_in,
                              void* d_out, int out_size, void* d_ws, size_t ws_size,
                              hipStream_t stream)
{
    const float* x  = (const float*)d_in[0];
    const float* Wq = (const float*)d_in[1];
    const float* Wk = (const float*)d_in[2];
    const float* Wv = (const float*)d_in[3];
    const float* W1 = (const float*)d_in[4];
    const float* b1 = (const float*)d_in[5];
    const float* W2 = (const float*)d_in[6];
    const float* b2 = (const float*)d_in[7];
    float* out = (float*)d_out;

    char* ws = (char*)d_ws;
    float*          G   = (float*)(ws);                       // 1 KB
    unsigned short* W1h = (unsigned short*)(ws + 1024);       // 32 KB
    unsigned short* W2h = (unsigned short*)(ws + 1024 + 32768);
    float*          LT  = (float*)(ws + 1024 + 65536);        // 16 KB
    const size_t    off_pm = 131072;

    // K1 block count: prefer 512, shrink if workspace is small
    int k1_blocks = 512;
    const size_t per_block_bytes = 4096 * 2 * sizeof(float);  // 32 KB (pm+ps)
    while (k1_blocks > 1 && off_pm + (size_t)k1_blocks * per_block_bytes > ws_size)
        k1_blocks >>= 1;
    const int k1_bpb = 32768 / k1_blocks;
    float* pm = (float*)(ws + off_pm);
    float* ps = pm + (size_t)k1_blocks * 4096;

    k0_prep <<<1,    256, 0, stream>>>(Wq, Wk, W1, W2, G, W1h, W2h);
    k1_stats<<<k1_blocks, 256, 0, stream>>>(x, G, pm, ps, k1_bpb);
    k2_reduce<<<16,  256, 0, stream>>>(pm, ps, LT, k1_blocks);
    k3_main <<<1024, 256, 0, stream>>>(x, G, Wv, LT, W1h, b1, W2h, b2, out, 32);
}

// Round 3
// 3011.697 us; speedup vs baseline: 1.0276x; 1.0276x over previous
//
#include <hip/hip_runtime.h>
#include <stdint.h>
#include <math.h>

// ---------------------------------------------------------------------------
// Encoder: per-batch tiny attention with softmax over the BATCH axis (dim 0),
// joint [64,16] LayerNorm, 64 independent per-patch 2-layer MLPs, final LN.
//
// Round-2 redesign: NO v_readlane (SGPR-hazard poison, ~9x VALU blowup in r0).
// All cross-lane data goes through LDS uniform broadcasts (conflict-free).
// U = x@G and V = x@Wv computed cooperatively (thread = (row, 4-col slice)).
//
// K0: G = Wq @ Wk^T / 3 ; pack W1/W2 to bf16
// K1: per-block online softmax stats over batch chunks (LDS double-buffered)
// K2: combine partials -> L[k][q] = m + ln(denom)  (ILP-4)
// K3: fused per-batch: scores -> attn -> z -> LN -> MLP -> LN -> out
// ---------------------------------------------------------------------------

__device__ __forceinline__ float bf16_lo(unsigned u) { return __uint_as_float(u << 16); }
__device__ __forceinline__ float bf16_hi(unsigned u) { return __uint_as_float(u & 0xffff0000u); }

// ---------------------------------------------------------------- K0: prep
__global__ void k0_prep(const float* __restrict__ Wq, const float* __restrict__ Wk,
                        const float* __restrict__ W1, const float* __restrict__ W2,
                        float* __restrict__ G, unsigned short* __restrict__ W1h,
                        unsigned short* __restrict__ W2h)
{
    const int t = threadIdx.x;
    {
        const int i = t >> 4, j = t & 15;
        float acc = 0.f;
        #pragma unroll
        for (int d = 0; d < 16; ++d) acc = fmaf(Wq[i*16 + d], Wk[j*16 + d], acc);
        G[i*16 + j] = acc * (1.0f / 3.0f);
    }
    for (int idx = t; idx < 16384; idx += 256) {
        const unsigned u1 = __float_as_uint(W1[idx]);   // round-to-nearest-even bf16
        W1h[idx] = (unsigned short)((u1 + 0x7fffu + ((u1 >> 16) & 1u)) >> 16);
        const unsigned u2 = __float_as_uint(W2[idx]);
        W2h[idx] = (unsigned short)((u2 + 0x7fffu + ((u2 >> 16) & 1u)) >> 16);
    }
}

// ------------------------------------------------- K1: online softmax stats
// lane = q; wave w owns k in [16w, 16w+16). Scores via LDS broadcast of x rows.
// x and U double-buffered in LDS -> single barrier per batch is race-free.
__global__ __launch_bounds__(256, 4) void k1_stats(
    const float* __restrict__ x, const float* __restrict__ G,
    float* __restrict__ pm, float* __restrict__ ps, int batches_per_block)
{
    __shared__ float G_lds[256];
    __shared__ float xb_lds[2][1024];
    __shared__ float U_lds[2][1280];        // [64][20] padded rows

    const int t = threadIdx.x, lane = t & 63, w = t >> 6, o0 = w << 2;
    if (t < 64) ((float4*)G_lds)[t] = ((const float4*)G)[t];

    float m_r[16], s_r[16];
    #pragma unroll
    for (int kk = 0; kk < 16; ++kk) { m_r[kk] = -INFINITY; s_r[kk] = 0.f; }
    __syncthreads();

    const size_t b0 = (size_t)blockIdx.x * batches_per_block;
    for (int bi = 0; bi < batches_per_block; ++bi) {
        const float* xb = x + (b0 + bi) * 1024;
        float* xl = xb_lds[bi & 1];
        float* Ul = U_lds[bi & 1];
        ((float4*)xl)[t] = ((const float4*)xb)[t];          // coalesced stage
        // own row of x (from global; L1/L2-hot)
        float xr[16];
        #pragma unroll
        for (int c = 0; c < 4; ++c) {
            const float4 v = ((const float4*)(xb + lane*16))[c];
            xr[4*c+0] = v.x; xr[4*c+1] = v.y; xr[4*c+2] = v.z; xr[4*c+3] = v.w;
        }
        // coop U: this thread computes U[lane][o0..o0+3]
        float u0 = 0.f, u1 = 0.f, u2 = 0.f, u3 = 0.f;
        #pragma unroll
        for (int i = 0; i < 16; ++i) {
            const float4 g = *(const float4*)&G_lds[i*16 + o0];   // broadcast
            u0 = fmaf(xr[i], g.x, u0); u1 = fmaf(xr[i], g.y, u1);
            u2 = fmaf(xr[i], g.z, u2); u3 = fmaf(xr[i], g.w, u3);
        }
        *(float4*)&Ul[lane*20 + o0] = make_float4(u0, u1, u2, u3);
        __syncthreads();
        // own U row back
        float Ur[16];
        #pragma unroll
        for (int c = 0; c < 4; ++c) {
            const float4 uu = *(const float4*)&Ul[lane*20 + 4*c];
            Ur[4*c+0] = uu.x; Ur[4*c+1] = uu.y; Ur[4*c+2] = uu.z; Ur[4*c+3] = uu.w;
        }
        #pragma unroll
        for (int kk = 0; kk < 16; ++kk) {
            const int k = (w << 4) + kk;
            float s0 = 0.f, s1 = 0.f, s2 = 0.f, s3 = 0.f;
            #pragma unroll
            for (int c = 0; c < 4; ++c) {
                const float4 xv = *(const float4*)&xl[k*16 + 4*c];  // broadcast
                s0 = fmaf(xv.x, Ur[4*c+0], s0); s1 = fmaf(xv.y, Ur[4*c+1], s1);
                s2 = fmaf(xv.z, Ur[4*c+2], s2); s3 = fmaf(xv.w, Ur[4*c+3], s3);
            }
            const float s = (s0 + s1) + (s2 + s3);
            if (s <= m_r[kk]) {
                s_r[kk] += __expf(s - m_r[kk]);
            } else {
                s_r[kk] = fmaf(s_r[kk], __expf(m_r[kk] - s), 1.0f);
                m_r[kk] = s;
            }
        }
    }
    float* pmb = pm + (size_t)blockIdx.x * 4096;
    float* psb = ps + (size_t)blockIdx.x * 4096;
    #pragma unroll
    for (int kk = 0; kk < 16; ++kk) {
        const int k = (w << 4) + kk;
        pmb[k*64 + lane] = m_r[kk];
        psb[k*64 + lane] = s_r[kk];
    }
}

// ------------------------------------------------ K2: combine -> L[k*64+q]
__global__ void k2_reduce(const float* __restrict__ pm, const float* __restrict__ ps,
                          float* __restrict__ LT, int nblocks)
{
    const int tid = blockIdx.x * 256 + threadIdx.x;   // 0..4095 == k*64+q
    float m[4], s[4];
    #pragma unroll
    for (int u = 0; u < 4; ++u) { m[u] = -INFINITY; s[u] = 0.f; }
    int blk = 0;
    for (; blk + 4 <= nblocks; blk += 4) {
        #pragma unroll
        for (int u = 0; u < 4; ++u) {
            const float mb = pm[(size_t)(blk + u) * 4096 + tid];
            const float sb = ps[(size_t)(blk + u) * 4096 + tid];
            if (mb <= m[u]) {
                s[u] += sb * __expf(mb - m[u]);
            } else {
                s[u] = fmaf(s[u], __expf(m[u] - mb), sb);
                m[u] = mb;
            }
        }
    }
    for (; blk < nblocks; ++blk) {
        const float mb = pm[(size_t)blk * 4096 + tid];
        const float sb = ps[(size_t)blk * 4096 + tid];
        if (mb <= m[0]) { s[0] += sb * __expf(mb - m[0]); }
        else { s[0] = fmaf(s[0], __expf(m[0] - mb), sb); m[0] = mb; }
    }
    #pragma unroll
    for (int u = 1; u < 4; ++u) {
        if (m[u] <= m[0]) { s[0] += s[u] * __expf(m[u] - m[0]); }
        else { s[0] = fmaf(s[0], __expf(m[0] - m[u]), s[u]); m[0] = m[u]; }
    }
    LT[tid] = m[0] + __logf(s[0]);
}

// --------------------------------------------------------- K3: fused output
__global__ __launch_bounds__(256, 3) void k3_main(
    const float* __restrict__ x, const float* __restrict__ G,
    const float* __restrict__ Wv, const float* __restrict__ LT,
    const unsigned short* __restrict__ W1h, const float* __restrict__ b1,
    const unsigned short* __restrict__ W2h, const float* __restrict__ b2,
    float* __restrict__ out, int batches_per_block)
{
    __shared__ float G_lds[256];
    __shared__ float Wv_lds[256];
    __shared__ float x_lds[1024];
    __shared__ float U_lds[1280];           // [64][20]
    __shared__ float V_lds[1280];           // [64][20]
    __shared__ float zp_lds[5120];          // [4][64][20]; y aliases [0], h aliases [1]
    __shared__ float red1[4][2];
    __shared__ float red2[4][2];

    const int t = threadIdx.x, lane = t & 63, w = t >> 6, o0 = w << 2;
    if (t < 64)       ((float4*)G_lds)[t]        = ((const float4*)G)[t];
    else if (t < 128) ((float4*)Wv_lds)[t - 64]  = ((const float4*)Wv)[t - 64];

    // resident per-thread MLP weights (bf16 packed): W1[p=lane][i][o0..o0+3]
    uint2 w1r[16], w2r[16];
    const uint2* W1v = (const uint2*)W1h;
    const uint2* W2v = (const uint2*)W2h;
    #pragma unroll
    for (int i = 0; i < 16; ++i) {
        const int eo = (lane*256 + i*16 + o0) >> 2;
        w1r[i] = W1v[eo];
        w2r[i] = W2v[eo];
    }
    const float4 b1r = *(const float4*)(b1 + lane*16 + o0);
    const float4 b2r = *(const float4*)(b2 + lane*16 + o0);
    float LTr[16];
    #pragma unroll
    for (int kk = 0; kk < 16; ++kk) LTr[kk] = LT[((w << 4) + kk)*64 + lane];
    __syncthreads();

    for (int bi = 0; bi < batches_per_block; ++bi) {
        const size_t b = (size_t)blockIdx.x * batches_per_block + bi;
        const float* xb = x + b * 1024;
        ((float4*)x_lds)[t] = ((const float4*)xb)[t];       // coalesced stage
        float xr[16];
        #pragma unroll
        for (int c = 0; c < 4; ++c) {
            const float4 v = ((const float4*)(xb + lane*16))[c];
            xr[4*c+0] = v.x; xr[4*c+1] = v.y; xr[4*c+2] = v.z; xr[4*c+3] = v.w;
        }
        // coop U and V: this thread computes row=lane, cols o0..o0+3 of each
        float u0=0.f,u1=0.f,u2=0.f,u3=0.f, v0=0.f,v1=0.f,v2=0.f,v3=0.f;
        #pragma unroll
        for (int i = 0; i < 16; ++i) {
            const float4 g  = *(const float4*)&G_lds[i*16 + o0];
            const float4 wv = *(const float4*)&Wv_lds[i*16 + o0];
            const float xi = xr[i];
            u0 = fmaf(xi, g.x,  u0); u1 = fmaf(xi, g.y,  u1);
            u2 = fmaf(xi, g.z,  u2); u3 = fmaf(xi, g.w,  u3);
            v0 = fmaf(xi, wv.x, v0); v1 = fmaf(xi, wv.y, v1);
            v2 = fmaf(xi, wv.z, v2); v3 = fmaf(xi, wv.w, v3);
        }
        *(float4*)&U_lds[lane*20 + o0] = make_float4(u0,u1,u2,u3);
        *(float4*)&V_lds[lane*20 + o0] = make_float4(v0,v1,v2,v3);
        __syncthreads();                                    // B1: x,U,V ready

        float Ur[16];
        #pragma unroll
        for (int c = 0; c < 4; ++c) {
            const float4 uu = *(const float4*)&U_lds[lane*20 + 4*c];
            Ur[4*c+0] = uu.x; Ur[4*c+1] = uu.y; Ur[4*c+2] = uu.z; Ur[4*c+3] = uu.w;
        }
        float z[16];
        #pragma unroll
        for (int d = 0; d < 16; ++d) z[d] = 0.f;
        #pragma unroll
        for (int kk = 0; kk < 16; ++kk) {
            const int k = (w << 4) + kk;
            float s0=0.f,s1=0.f,s2=0.f,s3=0.f;
            #pragma unroll
            for (int c = 0; c < 4; ++c) {
                const float4 xv = *(const float4*)&x_lds[k*16 + 4*c];   // broadcast
                s0 = fmaf(xv.x, Ur[4*c+0], s0); s1 = fmaf(xv.y, Ur[4*c+1], s1);
                s2 = fmaf(xv.z, Ur[4*c+2], s2); s3 = fmaf(xv.w, Ur[4*c+3], s3);
            }
            const float s = (s0 + s1) + (s2 + s3);
            const float p = __expf(s - LTr[kk]);            // s <= max => no overflow
            #pragma unroll
            for (int c = 0; c < 4; ++c) {
                const float4 vv = *(const float4*)&V_lds[k*20 + 4*c];   // broadcast
                z[4*c+0] = fmaf(p, vv.x, z[4*c+0]); z[4*c+1] = fmaf(p, vv.y, z[4*c+1]);
                z[4*c+2] = fmaf(p, vv.z, z[4*c+2]); z[4*c+3] = fmaf(p, vv.w, z[4*c+3]);
            }
        }
        #pragma unroll
        for (int c = 0; c < 4; ++c)
            *(float4*)&zp_lds[w*1280 + lane*20 + 4*c] =
                make_float4(z[4*c+0], z[4*c+1], z[4*c+2], z[4*c+3]);
        __syncthreads();                                    // B2: z partials ready

        // t = x + z (thread owns (q=lane, d=o0..o0+3))
        float tv[4];
        {
            const float4 xre = ((const float4*)(xb + lane*16))[w];
            const float4 a = *(const float4*)&zp_lds[0*1280 + lane*20 + o0];
            const float4 bq= *(const float4*)&zp_lds[1*1280 + lane*20 + o0];
            const float4 cq= *(const float4*)&zp_lds[2*1280 + lane*20 + o0];
            const float4 dq= *(const float4*)&zp_lds[3*1280 + lane*20 + o0];
            tv[0] = a.x + bq.x + cq.x + dq.x + xre.x;
            tv[1] = a.y + bq.y + cq.y + dq.y + xre.y;
            tv[2] = a.z + bq.z + cq.z + dq.z + xre.z;
            tv[3] = a.w + bq.w + cq.w + dq.w + xre.w;
        }
        // LN1 over all 1024 elements
        float sm = tv[0] + tv[1] + tv[2] + tv[3];
        float sq = fmaf(tv[0], tv[0], fmaf(tv[1], tv[1], fmaf(tv[2], tv[2], tv[3]*tv[3])));
        #pragma unroll
        for (int off = 1; off < 64; off <<= 1) {
            sm += __shfl_xor(sm, off);
            sq += __shfl_xor(sq, off);
        }
        if (lane == 0) { red1[w][0] = sm; red1[w][1] = sq; }
        __syncthreads();                                    // B3: red1 ready
        {
            const float S  = red1[0][0] + red1[1][0] + red1[2][0] + red1[3][0];
            const float SS = red1[0][1] + red1[1][1] + red1[2][1] + red1[3][1];
            const float mean = S * (1.f/1024.f);
            const float var  = SS * (1.f/1024.f) - mean*mean;
            const float rinv = rsqrtf(var + 1e-5f);
            *(float4*)&zp_lds[lane*20 + o0] = make_float4(   // y -> zp[0] region
                (tv[0]-mean)*rinv, (tv[1]-mean)*rinv, (tv[2]-mean)*rinv, (tv[3]-mean)*rinv);
        }
        __syncthreads();                                    // B4: y ready

        // MLP layer 1: h = relu(y @ W1[p] + b1[p]), p = lane
        float yr[16];
        #pragma unroll
        for (int c = 0; c < 4; ++c) {
            const float4 yv = *(const float4*)&zp_lds[lane*20 + 4*c];
            yr[4*c+0] = yv.x; yr[4*c+1] = yv.y; yr[4*c+2] = yv.z; yr[4*c+3] = yv.w;
        }
        float h0 = b1r.x, h1 = b1r.y, h2 = b1r.z, h3 = b1r.w;
        #pragma unroll
        for (int i = 0; i < 16; ++i) {
            const float yi = yr[i];
            const uint2 ww = w1r[i];
            h0 = fmaf(yi, bf16_lo(ww.x), h0);
            h1 = fmaf(yi, bf16_hi(ww.x), h1);
            h2 = fmaf(yi, bf16_lo(ww.y), h2);
            h3 = fmaf(yi, bf16_hi(ww.y), h3);
        }
        h0 = fmaxf(h0, 0.f); h1 = fmaxf(h1, 0.f); h2 = fmaxf(h2, 0.f); h3 = fmaxf(h3, 0.f);
        *(float4*)&zp_lds[1280 + lane*20 + o0] = make_float4(h0,h1,h2,h3);  // h -> zp[1]
        __syncthreads();                                    // B5: h ready

        // MLP layer 2
        float hr[16];
        #pragma unroll
        for (int c = 0; c < 4; ++c) {
            const float4 hv = *(const float4*)&zp_lds[1280 + lane*20 + 4*c];
            hr[4*c+0] = hv.x; hr[4*c+1] = hv.y; hr[4*c+2] = hv.z; hr[4*c+3] = hv.w;
        }
        float g0 = b2r.x, g1 = b2r.y, g2 = b2r.z, g3 = b2r.w;
        #pragma unroll
        for (int i = 0; i < 16; ++i) {
            const float hi = hr[i];
            const uint2 ww = w2r[i];
            g0 = fmaf(hi, bf16_lo(ww.x), g0);
            g1 = fmaf(hi, bf16_hi(ww.x), g1);
            g2 = fmaf(hi, bf16_lo(ww.y), g2);
            g3 = fmaf(hi, bf16_hi(ww.y), g3);
        }
        g0 = fmaxf(g0, 0.f); g1 = fmaxf(g1, 0.f); g2 = fmaxf(g2, 0.f); g3 = fmaxf(g3, 0.f);

        // residual + LN2
        const float4 yre = *(const float4*)&zp_lds[lane*20 + o0];
        float sv[4];
        sv[0] = g0 + yre.x; sv[1] = g1 + yre.y; sv[2] = g2 + yre.z; sv[3] = g3 + yre.w;
        float sm2 = sv[0] + sv[1] + sv[2] + sv[3];
        float sq2 = fmaf(sv[0], sv[0], fmaf(sv[1], sv[1], fmaf(sv[2], sv[2], sv[3]*sv[3])));
        #pragma unroll
        for (int off = 1; off < 64; off <<= 1) {
            sm2 += __shfl_xor(sm2, off);
            sq2 += __shfl_xor(sq2, off);
        }
        if (lane == 0) { red2[w][0] = sm2; red2[w][1] = sq2; }
        __syncthreads();                                    // B6: red2 ready
        {
            const float S  = red2[0][0] + red2[1][0] + red2[2][0] + red2[3][0];
            const float SS = red2[0][1] + red2[1][1] + red2[2][1] + red2[3][1];
            const float mean = S * (1.f/1024.f);
            const float var  = SS * (1.f/1024.f) - mean*mean;
            const float rinv = rsqrtf(var + 1e-5f);
            float4 ov;
            ov.x = (sv[0] - mean) * rinv;
            ov.y = (sv[1] - mean) * rinv;
            ov.z = (sv[2] - mean) * rinv;
            ov.w = (sv[3] - mean) * rinv;
            *(float4*)(out + b*1024 + lane*16 + o0) = ov;
        }
        // no trailing barrier needed: next batch's LDS writes are ordered
        // after every thread passes B1(next), which follows B6(this).
    }
}

// ---------------------------------------------------------------------------
extern "C" void kernel_launch(void* const* d_in, const int* in_sizes, int n_in,
                              void* d_out, int out_size, void* d_ws, size_t ws_size,
                              hipStream_t stream)
{
    const float* x  = (const float*)d_in[0];
    const float* Wq = (const float*)d_in[1];
    const float* Wk = (const float*)d_in[2];
    const float* Wv = (const float*)d_in[3];
    const float* W1 = (const float*)d_in[4];
    const float* b1 = (const float*)d_in[5];
    const float* W2 = (const float*)d_in[6];
    const float* b2 = (const float*)d_in[7];
    float* out = (float*)d_out;

    char* ws = (char*)d_ws;
    float*          G   = (float*)(ws);                       // 1 KB
    unsigned short* W1h = (unsigned short*)(ws + 1024);       // 32 KB
    unsigned short* W2h = (unsigned short*)(ws + 1024 + 32768);
    float*          LT  = (float*)(ws + 1024 + 65536);        // 16 KB
    const size_t    off_pm = 131072;

    // K1 block count: prefer 1024, shrink if workspace is small
    int k1_blocks = 1024;
    const size_t per_block_bytes = 4096 * 2 * sizeof(float);  // 32 KB (pm+ps)
    while (k1_blocks > 4 && off_pm + (size_t)k1_blocks * per_block_bytes > ws_size)
        k1_blocks >>= 1;
    const int k1_bpb = 32768 / k1_blocks;
    float* pm = (float*)(ws + off_pm);
    float* ps = pm + (size_t)k1_blocks * 4096;

    k0_prep <<<1,    256, 0, stream>>>(Wq, Wk, W1, W2, G, W1h, W2h);
    k1_stats<<<k1_blocks, 256, 0, stream>>>(x, G, pm, ps, k1_bpb);
    k2_reduce<<<16,  256, 0, stream>>>(pm, ps, LT, k1_blocks);
    k3_main <<<1024, 256, 0, stream>>>(x, G, Wv, LT, W1h, b1, W2h, b2, out, 32);
}